// Round 4
// baseline (1149.014 us; speedup 1.0000x reference)
//
#include <hip/hip_runtime.h>
#include <hip/hip_bf16.h>
#include <math.h>

// Problem constants (fixed by the reference)
#define NB    4096      // number of anchors  (B / GROUP)
#define BB    20480     // total rows of inputs = columns of sim
#define DD    512       // feature dim
#define EPc    0.1f
#define BETAc  10.0f
#define ALPHAc 2.0f
#define LMDAc  1.0f
// LSE shift for the double-precision neg-sum. Masked args BETA*(s-1) span
// roughly [-700, 1360] (sim std ~22.6, global max ~137). exp(arg-1400) is
// <= e^-40 (finite) for the largest and representable (>= ~e^-745) for every
// row-dominant term; tiny terms underflow harmlessly (< e^-135 relative).
#define SHIFT  1400.0

// ---- monotone float <-> uint key (for atomicMax on float incl. negatives) ----
__device__ __forceinline__ unsigned fenc(float x) {
    unsigned b = __float_as_uint(x);
    return (b & 0x80000000u) ? ~b : (b | 0x80000000u);
}
__device__ __forceinline__ float fdec(unsigned k) {
    unsigned b = (k & 0x80000000u) ? (k ^ 0x80000000u) : ~k;
    return __uint_as_float(b);
}

// ============================================================================
// Kernel 1: pos[i][g-1] = f_i . inputs[5i+g], g=1..4 ; posmin[i] = min_g pos
// ============================================================================
__global__ __launch_bounds__(256) void pos_kernel(const float* __restrict__ inp,
        float* __restrict__ pos, float* __restrict__ posmin)
{
    const int wid  = threadIdx.x >> 6;
    const int lane = threadIdx.x & 63;
    const int i = blockIdx.x * 4 + wid;           // grid = 1024 -> i in [0,4096)
    const float* f = inp + (size_t)(5 * i) * DD + lane * 8;
    float4 fa = *(const float4*)(f);
    float4 fb = *(const float4*)(f + 4);
    float pmin = INFINITY;
    #pragma unroll
    for (int g = 1; g < 5; ++g) {
        const float* x = inp + (size_t)(5 * i + g) * DD + lane * 8;
        float4 xa = *(const float4*)(x);
        float4 xb = *(const float4*)(x + 4);
        float s = fa.x*xa.x + fa.y*xa.y + fa.z*xa.z + fa.w*xa.w
                + fb.x*xb.x + fb.y*xb.y + fb.z*xb.z + fb.w*xb.w;
        #pragma unroll
        for (int m = 1; m < 64; m <<= 1) s += __shfl_xor(s, m, 64);
        if (lane == 0) pos[i * 4 + (g - 1)] = s;
        pmin = fminf(pmin, s);
    }
    if (lane == 0) posmin[i] = pmin;
}

// ============================================================================
// Kernel 2: fused sim-tile GEMM + per-row {max (excl. own group), stable LSE
//           partial of exp(BETA*(s-1)) (as double, shifted), count}.
// Tile: BM=128 anchors x BN=128 cols, BK=32. 256 threads, micro-tile 16x4.
// ============================================================================
#define BM 128
#define BN 128
#define BK 32
#define LDP 132

__global__ __launch_bounds__(256) void sim_kernel(const float* __restrict__ inp,
        const float* __restrict__ posmin, unsigned* __restrict__ negkey,
        double* __restrict__ msum, unsigned* __restrict__ cntn)
{
    __shared__ float As[BK * LDP];
    __shared__ float Bs[BK * LDP];
    const int t  = threadIdx.x;
    const int bj = blockIdx.x % (BB / BN);   // 160 col tiles
    const int bi = blockIdx.x / (BB / BN);   // 32 row tiles
    const int i0 = bi * BM;
    const int c0 = bj * BN;
    const int tx = t & 31;                   // 0..31 -> 4 cols each
    const int ty = t >> 5;                   // 0..7  -> 16 rows each
    const int m0 = ty * 16;
    const int n0 = tx * 4;

    float acc[16][4];
    #pragma unroll
    for (int a = 0; a < 16; ++a)
        #pragma unroll
        for (int b = 0; b < 4; ++b) acc[a][b] = 0.f;

    for (int kb = 0; kb < DD; kb += BK) {
        __syncthreads();
        #pragma unroll
        for (int v = 0; v < 4; ++v) {
            int idx = t + v * 256;           // 0..1023 = 128 rows x 8 float4
            int fi = idx >> 3;
            int k4 = idx & 7;
            float4 a = *(const float4*)(inp + (size_t)(5 * (i0 + fi)) * DD + kb + k4 * 4);
            float4 b = *(const float4*)(inp + (size_t)(c0 + fi)      * DD + kb + k4 * 4);
            As[(k4 * 4 + 0) * LDP + fi] = a.x;
            As[(k4 * 4 + 1) * LDP + fi] = a.y;
            As[(k4 * 4 + 2) * LDP + fi] = a.z;
            As[(k4 * 4 + 3) * LDP + fi] = a.w;
            Bs[(k4 * 4 + 0) * LDP + fi] = b.x;
            Bs[(k4 * 4 + 1) * LDP + fi] = b.y;
            Bs[(k4 * 4 + 2) * LDP + fi] = b.z;
            Bs[(k4 * 4 + 3) * LDP + fi] = b.w;
        }
        __syncthreads();
        #pragma unroll 8
        for (int k = 0; k < BK; ++k) {
            const float* ar = &As[k * LDP + m0];
            float4 a0 = *(const float4*)(ar + 0);
            float4 a1 = *(const float4*)(ar + 4);
            float4 a2 = *(const float4*)(ar + 8);
            float4 a3 = *(const float4*)(ar + 12);
            float4 bv = *(const float4*)(&Bs[k * LDP + n0]);
            float am[16] = { a0.x,a0.y,a0.z,a0.w, a1.x,a1.y,a1.z,a1.w,
                             a2.x,a2.y,a2.z,a2.w, a3.x,a3.y,a3.z,a3.w };
            float bn[4]  = { bv.x, bv.y, bv.z, bv.w };
            #pragma unroll
            for (int mm = 0; mm < 16; ++mm)
                #pragma unroll
                for (int nn = 0; nn < 4; ++nn)
                    acc[mm][nn] = fmaf(am[mm], bn[nn], acc[mm][nn]);
        }
    }

    // ---- fused epilogue: per-row max / stable LSE partial / count ----
    #pragma unroll
    for (int mm = 0; mm < 16; ++mm) {
        const int i = i0 + m0 + mm;
        const float th = posmin[i] - EPc;     // strict >
        float vmax = -INFINITY;               // max over non-own columns
        float lM   = -INFINITY;               // max masked arg BETA*(s-1)
        float lS   = 0.f;                     // sum exp(arg - lM)
        int   vcnt = 0;
        float args[4]; bool msk[4];
        #pragma unroll
        for (int nn = 0; nn < 4; ++nn) {
            const int c = c0 + n0 + nn;
            const int jg = c / 5;
            const float s = acc[mm][nn];
            bool nonown = (jg != i);
            msk[nn] = nonown && (s > th);
            args[nn] = BETAc * (s - LMDAc);
            if (nonown) vmax = fmaxf(vmax, s);
            if (msk[nn]) { vcnt += 1; lM = fmaxf(lM, args[nn]); }
        }
        #pragma unroll
        for (int nn = 0; nn < 4; ++nn)
            if (msk[nn]) lS += __expf(args[nn] - lM);
        // reduce across the 32-lane tx group
        #pragma unroll
        for (int m = 1; m < 32; m <<= 1) {
            vmax  = fmaxf(vmax, __shfl_xor(vmax, m, 64));
            vcnt += __shfl_xor(vcnt, m, 64);
            float oM = __shfl_xor(lM, m, 64);
            float oS = __shfl_xor(lS, m, 64);
            if (oS != 0.f) {
                if (lS == 0.f)      { lM = oM; lS = oS; }
                else if (lM >= oM)  { lS += oS * __expf(oM - lM); }
                else                { lS = oS + lS * __expf(lM - oM); lM = oM; }
            }
        }
        if ((t & 31) == 0) {
            atomicMax(&negkey[i], fenc(vmax));
            atomicAdd(&cntn[i], (unsigned)vcnt);
            if (lS > 0.f) {
                // D = exp(lM - SHIFT) * lS, guaranteed finite:
                // clamp the exponent arg (adversarial safety) and the product.
                double e = (double)lM - SHIFT;
                if (e > 690.0) e = 690.0;
                double D = exp(e) * (double)lS;
                if (!(D < 1e300)) D = 1e300;      // also catches nan
                atomicAdd(&msum[i], D);
            }
        }
    }
}

// ============================================================================
// Kernel 3: finalize. Stable loss_p + loss_n per row; reduce to 3 scalars.
// ============================================================================
__global__ __launch_bounds__(1024) void fin_kernel(const float* __restrict__ pos,
        const unsigned* __restrict__ negkey, const double* __restrict__ msum,
        const unsigned* __restrict__ cntn, float* __restrict__ out)
{
    const int t = threadIdx.x;
    double lossAcc = 0.0;
    int pAcc = 0, nAcc = 0;
    for (int r = t; r < NB; r += 1024) {
        const float negmax = fdec(negkey[r]);
        const float thr = negmax + EPc;       // strict <
        // ---- loss_p: <=4 terms, stable ----
        float Mp = -INFINITY; int pc = 0;
        float pa[4]; bool pm[4];
        #pragma unroll
        for (int g = 0; g < 4; ++g) {
            const float p = pos[r * 4 + g];
            pa[g] = -ALPHAc * (p - LMDAc);
            pm[g] = (p < thr);
            if (pm[g]) { pc += 1; Mp = fmaxf(Mp, pa[g]); }
        }
        double lp = 0.0;
        if (pc > 0) {
            float sp = 0.f;
            #pragma unroll
            for (int g = 0; g < 4; ++g)
                if (pm[g]) sp += __expf(pa[g] - Mp);
            double a = (double)Mp + log((double)sp);   // log of total sum
            lp = (a > 30.0 ? a : log1p(exp(a))) / (double)ALPHAc;
        }
        // ---- loss_n: from shifted double sum ----
        double ln = 0.0;
        double Dsum = msum[r];
        if (Dsum > 0.0) {
            double a = SHIFT + log(Dsum);
            ln = (a > 30.0 ? a : log1p(exp(a))) / (double)BETAc;
        }
        double contrib = lp + ln;
        if (!(contrib < 1e30)) contrib = 1e30;   // finite-guard (also nan)
        lossAcc += contrib;
        pAcc += pc;
        nAcc += (int)cntn[r];
    }
    __shared__ double sl[1024];
    __shared__ int    sp_[1024];
    __shared__ int    sn_[1024];
    sl[t] = lossAcc; sp_[t] = pAcc; sn_[t] = nAcc;
    __syncthreads();
    for (int s = 512; s > 0; s >>= 1) {
        if (t < s) { sl[t] += sl[t + s]; sp_[t] += sp_[t + s]; sn_[t] += sn_[t + s]; }
        __syncthreads();
    }
    if (t == 0) {
        double loss = sl[0] / 4096.0;
        if (!(loss < 1e30)) loss = 1e30;         // absolute finite-guard
        out[0] = (float)loss;                    // loss (finite, stable LSE)
        out[1] = (float)sp_[0] / 16384.0f;       // p_num / (4*N)
        out[2] = (float)sn_[0] / 83865600.0f;    // n_num / ((B-GROUP)*N)
    }
}

// ============================================================================
extern "C" void kernel_launch(void* const* d_in, const int* in_sizes, int n_in,
                              void* d_out, int out_size, void* d_ws, size_t ws_size,
                              hipStream_t stream)
{
    (void)in_sizes; (void)n_in; (void)out_size; (void)ws_size;
    const float* inp = (const float*)d_in[0];   // (20480, 512) f32; targets unused
    char* ws = (char*)d_ws;
    // ws layout (bytes):
    //   [0      , 65536 )  pos      : 4096*4 f32
    //   [65536  , 81920 )  posmin   : 4096 f32
    //   [81920  , 98304 )  negkey   : 4096 u32   (monotone-encoded float max)
    //   [98304  , 131072)  msum     : 4096 f64   (shifted LSE sums)
    //   [131072 , 147456)  cntn     : 4096 u32
    float*    pos    = (float*)   (ws);
    float*    posmin = (float*)   (ws + 65536);
    unsigned* negkey = (unsigned*)(ws + 81920);
    double*   msum   = (double*)  (ws + 98304);
    unsigned* cntn   = (unsigned*)(ws + 131072);
    float*    out    = (float*)d_out;

    // zero the accumulated arrays (negkey=0 is below every real key)
    hipMemsetAsync(ws + 81920, 0, 65536, stream);

    hipLaunchKernelGGL(pos_kernel, dim3(NB / 4), dim3(256), 0, stream, inp, pos, posmin);
    hipLaunchKernelGGL(sim_kernel, dim3((NB / BM) * (BB / BN)), dim3(256), 0, stream,
                       inp, posmin, negkey, msum, cntn);
    hipLaunchKernelGGL(fin_kernel, dim3(1), dim3(1024), 0, stream, pos, negkey, msum, cntn, out);
}

// Round 5
// 582.291 us; speedup vs baseline: 1.9733x; 1.9733x over previous
//
#include <hip/hip_runtime.h>
#include <hip/hip_bf16.h>
#include <math.h>

// Problem constants (fixed by the reference)
#define NB    4096      // number of anchors  (B / GROUP)
#define BB    20480     // total rows of inputs = columns of sim
#define DD    512       // feature dim
#define EPc    0.1f
#define BETAc  10.0f
#define ALPHAc 2.0f
#define LMDAc  1.0f
// LSE shift: masked args BETA*(s-1) span ~[-700, 1400]. exp(arg-1400) finite
// for the largest, representable for every row-dominant term.
#define SHIFT  1400.0

typedef __attribute__((ext_vector_type(8))) short bf16x8;   // 8 bf16 (4 VGPRs)
typedef __attribute__((ext_vector_type(4))) float f32x4;    // MFMA accumulator

// ---- monotone float <-> uint key (for atomicMax on float incl. negatives) ----
__device__ __forceinline__ unsigned fenc(float x) {
    unsigned b = __float_as_uint(x);
    return (b & 0x80000000u) ? ~b : (b | 0x80000000u);
}
__device__ __forceinline__ float fdec(unsigned k) {
    unsigned b = (k & 0x80000000u) ? (k ^ 0x80000000u) : ~k;
    return __uint_as_float(b);
}

// ============================================================================
// Kernel 1: pos[i][g-1] = f_i . inputs[5i+g], g=1..4 ; posmin[i] = min_g pos
// (kept in exact f32 — pos feeds the p-mask threshold directly)
// ============================================================================
__global__ __launch_bounds__(256) void pos_kernel(const float* __restrict__ inp,
        float* __restrict__ pos, float* __restrict__ posmin)
{
    const int wid  = threadIdx.x >> 6;
    const int lane = threadIdx.x & 63;
    const int i = blockIdx.x * 4 + wid;           // grid = 1024 -> i in [0,4096)
    const float* f = inp + (size_t)(5 * i) * DD + lane * 8;
    float4 fa = *(const float4*)(f);
    float4 fb = *(const float4*)(f + 4);
    float pmin = INFINITY;
    #pragma unroll
    for (int g = 1; g < 5; ++g) {
        const float* x = inp + (size_t)(5 * i + g) * DD + lane * 8;
        float4 xa = *(const float4*)(x);
        float4 xb = *(const float4*)(x + 4);
        float s = fa.x*xa.x + fa.y*xa.y + fa.z*xa.z + fa.w*xa.w
                + fb.x*xb.x + fb.y*xb.y + fb.z*xb.z + fb.w*xb.w;
        #pragma unroll
        for (int m = 1; m < 64; m <<= 1) s += __shfl_xor(s, m, 64);
        if (lane == 0) pos[i * 4 + (g - 1)] = s;
        pmin = fminf(pmin, s);
    }
    if (lane == 0) posmin[i] = pmin;
}

// ============================================================================
// f32 -> (hi, lo) bf16 split of 8 contiguous floats; packed as uint4 pair.
// sim ~= hi.hi + hi.lo + lo.hi  (lo.lo dropped: ~2e-5 relative -> ~5e-4 abs)
// ============================================================================
__device__ __forceinline__ void cvt8(const float* __restrict__ src,
                                     uint4* __restrict__ dhi, uint4* __restrict__ dlo)
{
    float4 x0 = *(const float4*)(src);
    float4 x1 = *(const float4*)(src + 4);
    float xs[8] = {x0.x, x0.y, x0.z, x0.w, x1.x, x1.y, x1.z, x1.w};
    unsigned h[4], l[4];
    #pragma unroll
    for (int p = 0; p < 4; ++p) {
        float a = xs[2*p], b = xs[2*p+1];
        __hip_bfloat16 ha = __float2bfloat16(a);
        __hip_bfloat16 hb = __float2bfloat16(b);
        unsigned short ba, bb;
        __builtin_memcpy(&ba, &ha, 2); __builtin_memcpy(&bb, &hb, 2);
        float fa = __uint_as_float((unsigned)ba << 16);
        float fb = __uint_as_float((unsigned)bb << 16);
        __hip_bfloat16 la = __float2bfloat16(a - fa);
        __hip_bfloat16 lb = __float2bfloat16(b - fb);
        unsigned short ca, cb;
        __builtin_memcpy(&ca, &la, 2); __builtin_memcpy(&cb, &lb, 2);
        h[p] = (unsigned)ba | ((unsigned)bb << 16);
        l[p] = (unsigned)ca | ((unsigned)cb << 16);
    }
    *dhi = make_uint4(h[0], h[1], h[2], h[3]);
    *dlo = make_uint4(l[0], l[1], l[2], l[3]);
}

// ============================================================================
// Kernel 2: MFMA sim-tile GEMM (split-bf16) + fused per-row epilogue.
// 128x128 tile, BK=32, 4 waves each owning a 64x64 block (4x4 frags 16x16x32).
// LDS: [row][chunk^((row>>2)&3)] XOR swizzle -> uniform bank coverage.
// ============================================================================
__global__ __launch_bounds__(256) void sim_mfma(const float* __restrict__ inp,
        const float* __restrict__ posmin, unsigned* __restrict__ negkey,
        double* __restrict__ msum, unsigned* __restrict__ cntn)
{
    __shared__ uint4 AsHi[128][4];
    __shared__ uint4 AsLo[128][4];
    __shared__ uint4 BsHi[128][4];
    __shared__ uint4 BsLo[128][4];

    const int t    = threadIdx.x;
    const int bj   = blockIdx.x % (BB / 128);   // 160 col tiles
    const int bi   = blockIdx.x / (BB / 128);   // 32 row tiles
    const int i0   = bi * 128;
    const int c0   = bj * 128;
    const int lane = t & 63;
    const int w    = t >> 6;                    // wave 0..3
    const int wr   = (w >> 1) * 64;             // wave row offset in tile
    const int wc   = (w & 1) * 64;              // wave col offset in tile
    const int l15  = lane & 15;
    const int l4   = lane >> 4;                 // k-chunk for MFMA frags

    f32x4 acc[4][4];
    #pragma unroll
    for (int a = 0; a < 4; ++a)
        #pragma unroll
        for (int b = 0; b < 4; ++b) acc[a][b] = (f32x4)0.f;

    const int r0  = t >> 2;                     // staging row (slot t)
    const int ch0 = t & 3;                      // staging chunk

    for (int kb = 0; kb < DD; kb += 32) {
        __syncthreads();
        #pragma unroll
        for (int half = 0; half < 2; ++half) {
            const int row = r0 + half * 64;
            const int cs  = ch0 ^ ((row >> 2) & 3);
            cvt8(inp + (size_t)(5 * (i0 + row)) * DD + kb + ch0 * 8,
                 &AsHi[row][cs], &AsLo[row][cs]);
            cvt8(inp + (size_t)(c0 + row) * DD + kb + ch0 * 8,
                 &BsHi[row][cs], &BsLo[row][cs]);
        }
        __syncthreads();

        bf16x8 bh[4], bl[4];
        #pragma unroll
        for (int fc = 0; fc < 4; ++fc) {
            const int col = wc + fc * 16 + l15;
            const int cs  = l4 ^ ((col >> 2) & 3);
            bh[fc] = *(const bf16x8*)&BsHi[col][cs];
            bl[fc] = *(const bf16x8*)&BsLo[col][cs];
        }
        #pragma unroll
        for (int fr = 0; fr < 4; ++fr) {
            const int row = wr + fr * 16 + l15;
            const int cs  = l4 ^ ((row >> 2) & 3);
            bf16x8 ah = *(const bf16x8*)&AsHi[row][cs];
            bf16x8 al = *(const bf16x8*)&AsLo[row][cs];
            #pragma unroll
            for (int fc = 0; fc < 4; ++fc) {
                acc[fr][fc] = __builtin_amdgcn_mfma_f32_16x16x32_bf16(ah, bh[fc], acc[fr][fc], 0, 0, 0);
                acc[fr][fc] = __builtin_amdgcn_mfma_f32_16x16x32_bf16(ah, bl[fc], acc[fr][fc], 0, 0, 0);
                acc[fr][fc] = __builtin_amdgcn_mfma_f32_16x16x32_bf16(al, bh[fc], acc[fr][fc], 0, 0, 0);
            }
        }
    }

    // ---- fused epilogue. C/D layout: col = lane&15, row = (lane>>4)*4 + reg ----
    #pragma unroll
    for (int fr = 0; fr < 4; ++fr) {
        #pragma unroll
        for (int reg = 0; reg < 4; ++reg) {
            const int i  = i0 + wr + fr * 16 + l4 * 4 + reg;
            const float th = posmin[i] - EPc;     // strict >
            float vmax = -INFINITY;
            float lM   = -INFINITY;
            float lS   = 0.f;
            int   vcnt = 0;
            float args[4]; bool msk[4];
            #pragma unroll
            for (int fc = 0; fc < 4; ++fc) {
                const int c = c0 + wc + fc * 16 + l15;
                const float s = acc[fr][fc][reg];
                const bool nonown = ((c / 5) != i);
                msk[fc]  = nonown && (s > th);
                args[fc] = BETAc * (s - LMDAc);
                if (nonown)  vmax = fmaxf(vmax, s);
                if (msk[fc]) { vcnt += 1; lM = fmaxf(lM, args[fc]); }
            }
            #pragma unroll
            for (int fc = 0; fc < 4; ++fc)
                if (msk[fc]) lS += __expf(args[fc] - lM);
            // reduce across the 16 lanes holding this row (xor 1,2,4,8)
            #pragma unroll
            for (int m = 1; m < 16; m <<= 1) {
                vmax  = fmaxf(vmax, __shfl_xor(vmax, m, 64));
                vcnt += __shfl_xor(vcnt, m, 64);
                float oM = __shfl_xor(lM, m, 64);
                float oS = __shfl_xor(lS, m, 64);
                if (oS != 0.f) {
                    if (lS == 0.f)      { lM = oM; lS = oS; }
                    else if (lM >= oM)  { lS += oS * __expf(oM - lM); }
                    else                { lS = oS + lS * __expf(lM - oM); lM = oM; }
                }
            }
            if (l15 == 0) {
                atomicMax(&negkey[i], fenc(vmax));
                atomicAdd(&cntn[i], (unsigned)vcnt);
                if (lS > 0.f) {
                    double e = (double)lM - SHIFT;
                    if (e > 690.0) e = 690.0;
                    double Dv = exp(e) * (double)lS;
                    if (!(Dv < 1e300)) Dv = 1e300;    // also catches nan
                    atomicAdd(&msum[i], Dv);
                }
            }
        }
    }
}

// ============================================================================
// Kernel 3: finalize. Stable loss_p + loss_n per row; reduce to 3 scalars.
// ============================================================================
__global__ __launch_bounds__(1024) void fin_kernel(const float* __restrict__ pos,
        const unsigned* __restrict__ negkey, const double* __restrict__ msum,
        const unsigned* __restrict__ cntn, float* __restrict__ out)
{
    const int t = threadIdx.x;
    double lossAcc = 0.0;
    int pAcc = 0, nAcc = 0;
    for (int r = t; r < NB; r += 1024) {
        const float negmax = fdec(negkey[r]);
        const float thr = negmax + EPc;       // strict <
        float Mp = -INFINITY; int pc = 0;
        float pa[4]; bool pm[4];
        #pragma unroll
        for (int g = 0; g < 4; ++g) {
            const float p = pos[r * 4 + g];
            pa[g] = -ALPHAc * (p - LMDAc);
            pm[g] = (p < thr);
            if (pm[g]) { pc += 1; Mp = fmaxf(Mp, pa[g]); }
        }
        double lp = 0.0;
        if (pc > 0) {
            float sp = 0.f;
            #pragma unroll
            for (int g = 0; g < 4; ++g)
                if (pm[g]) sp += __expf(pa[g] - Mp);
            double a = (double)Mp + log((double)sp);
            lp = (a > 30.0 ? a : log1p(exp(a))) / (double)ALPHAc;
        }
        double ln = 0.0;
        double Dsum = msum[r];
        if (Dsum > 0.0) {
            double a = SHIFT + log(Dsum);
            ln = (a > 30.0 ? a : log1p(exp(a))) / (double)BETAc;
        }
        double contrib = lp + ln;
        if (!(contrib < 1e30)) contrib = 1e30;   // finite-guard (also nan)
        lossAcc += contrib;
        pAcc += pc;
        nAcc += (int)cntn[r];
    }
    __shared__ double sl[1024];
    __shared__ int    sp_[1024];
    __shared__ int    sn_[1024];
    sl[t] = lossAcc; sp_[t] = pAcc; sn_[t] = nAcc;
    __syncthreads();
    for (int s = 512; s > 0; s >>= 1) {
        if (t < s) { sl[t] += sl[t + s]; sp_[t] += sp_[t + s]; sn_[t] += sn_[t + s]; }
        __syncthreads();
    }
    if (t == 0) {
        double loss = sl[0] / 4096.0;
        if (!(loss < 1e30)) loss = 1e30;         // absolute finite-guard
        out[0] = (float)loss;                    // loss (finite, stable LSE)
        out[1] = (float)sp_[0] / 16384.0f;       // p_num / (4*N)
        out[2] = (float)sn_[0] / 83865600.0f;    // n_num / ((B-GROUP)*N)
    }
}

// ============================================================================
extern "C" void kernel_launch(void* const* d_in, const int* in_sizes, int n_in,
                              void* d_out, int out_size, void* d_ws, size_t ws_size,
                              hipStream_t stream)
{
    (void)in_sizes; (void)n_in; (void)out_size; (void)ws_size;
    const float* inp = (const float*)d_in[0];   // (20480, 512) f32; targets unused
    char* ws = (char*)d_ws;
    // ws layout (bytes):
    //   [0      , 65536 )  pos      : 4096*4 f32
    //   [65536  , 81920 )  posmin   : 4096 f32
    //   [81920  , 98304 )  negkey   : 4096 u32   (monotone-encoded float max)
    //   [98304  , 131072)  msum     : 4096 f64   (shifted LSE sums)
    //   [131072 , 147456)  cntn     : 4096 u32
    float*    pos    = (float*)   (ws);
    float*    posmin = (float*)   (ws + 65536);
    unsigned* negkey = (unsigned*)(ws + 81920);
    double*   msum   = (double*)  (ws + 98304);
    unsigned* cntn   = (unsigned*)(ws + 131072);
    float*    out    = (float*)d_out;

    // zero the accumulated arrays (negkey=0 is below every real key)
    hipMemsetAsync(ws + 81920, 0, 65536, stream);

    hipLaunchKernelGGL(pos_kernel, dim3(NB / 4), dim3(256), 0, stream, inp, pos, posmin);
    hipLaunchKernelGGL(sim_mfma, dim3((NB / 128) * (BB / 128)), dim3(256), 0, stream,
                       inp, posmin, negkey, msum, cntn);
    hipLaunchKernelGGL(fin_kernel, dim3(1), dim3(1024), 0, stream, pos, negkey, msum, cntn, out);
}

// Round 6
// 535.899 us; speedup vs baseline: 2.1441x; 1.0866x over previous
//
#include <hip/hip_runtime.h>
#include <hip/hip_bf16.h>
#include <math.h>

// Problem constants (fixed by the reference)
#define NB    4096      // number of anchors  (B / GROUP)
#define BB    20480     // total rows of inputs = columns of sim
#define DD    512       // feature dim
#define EPc    0.1f
#define BETAc  10.0f
#define ALPHAc 2.0f
#define LMDAc  1.0f
// LSE shift: masked args BETA*(s-1) span ~[-700, 1400].
#define SHIFT  1400.0

typedef __attribute__((ext_vector_type(8))) short bf16x8;   // 8 bf16 (4 VGPRs)
typedef __attribute__((ext_vector_type(4))) float f32x4;    // MFMA accumulator
typedef unsigned int u32;

// global_load_lds, 16B per lane. LDS dest is wave-uniform base + lane*16 (m104);
// global src is per-lane (pre-swizzled there, rule 21).
#define GLOAD16(gp, lp) \
    __builtin_amdgcn_global_load_lds((const __attribute__((address_space(1))) u32*)(gp), \
                                     (__attribute__((address_space(3))) u32*)(lp), 16, 0, 0)

// ---- monotone float <-> uint key (for atomicMax on float incl. negatives) ----
__device__ __forceinline__ unsigned fenc(float x) {
    unsigned b = __float_as_uint(x);
    return (b & 0x80000000u) ? ~b : (b | 0x80000000u);
}
__device__ __forceinline__ float fdec(unsigned k) {
    unsigned b = (k & 0x80000000u) ? (k ^ 0x80000000u) : ~k;
    return __uint_as_float(b);
}

// ---- f32 pair -> packed bf16 hi / lo words ----
__device__ __forceinline__ void split2(float a, float b, u32* h, u32* l) {
    __hip_bfloat16 ha = __float2bfloat16(a);
    __hip_bfloat16 hb = __float2bfloat16(b);
    unsigned short ba, bb;
    __builtin_memcpy(&ba, &ha, 2); __builtin_memcpy(&bb, &hb, 2);
    float fa = __uint_as_float((u32)ba << 16);
    float fb = __uint_as_float((u32)bb << 16);
    __hip_bfloat16 la = __float2bfloat16(a - fa);
    __hip_bfloat16 lb = __float2bfloat16(b - fb);
    unsigned short ca, cb;
    __builtin_memcpy(&ca, &la, 2); __builtin_memcpy(&cb, &lb, 2);
    *h = (u32)ba | ((u32)bb << 16);
    *l = (u32)ca | ((u32)cb << 16);
}

// ============================================================================
// Kernel 0: split inputs into Hi/Lo bf16 arrays (row-major [BB][DD], packed).
// 5120 blocks x 256 threads x 8 floats = 10.49M elements exactly.
// ============================================================================
__global__ __launch_bounds__(256) void split_kernel(const float* __restrict__ inp,
        u32* __restrict__ hi, u32* __restrict__ lo)
{
    const size_t e = ((size_t)blockIdx.x * 256 + threadIdx.x) * 8;
    float4 x0 = *(const float4*)(inp + e);
    float4 x1 = *(const float4*)(inp + e + 4);
    u32 h[4], l[4];
    split2(x0.x, x0.y, &h[0], &l[0]);
    split2(x0.z, x0.w, &h[1], &l[1]);
    split2(x1.x, x1.y, &h[2], &l[2]);
    split2(x1.z, x1.w, &h[3], &l[3]);
    *(uint4*)(hi + e / 2) = make_uint4(h[0], h[1], h[2], h[3]);
    *(uint4*)(lo + e / 2) = make_uint4(l[0], l[1], l[2], l[3]);
}

// ============================================================================
// Kernel 1: pos[i][g-1] = f_i . inputs[5i+g] (exact f32); posmin[i] = min
// ============================================================================
__global__ __launch_bounds__(256) void pos_kernel(const float* __restrict__ inp,
        float* __restrict__ pos, float* __restrict__ posmin)
{
    const int wid  = threadIdx.x >> 6;
    const int lane = threadIdx.x & 63;
    const int i = blockIdx.x * 4 + wid;
    const float* f = inp + (size_t)(5 * i) * DD + lane * 8;
    float4 fa = *(const float4*)(f);
    float4 fb = *(const float4*)(f + 4);
    float pmin = INFINITY;
    #pragma unroll
    for (int g = 1; g < 5; ++g) {
        const float* x = inp + (size_t)(5 * i + g) * DD + lane * 8;
        float4 xa = *(const float4*)(x);
        float4 xb = *(const float4*)(x + 4);
        float s = fa.x*xa.x + fa.y*xa.y + fa.z*xa.z + fa.w*xa.w
                + fb.x*xb.x + fb.y*xb.y + fb.z*xb.z + fb.w*xb.w;
        #pragma unroll
        for (int m = 1; m < 64; m <<= 1) s += __shfl_xor(s, m, 64);
        if (lane == 0) pos[i * 4 + (g - 1)] = s;
        pmin = fminf(pmin, s);
    }
    if (lane == 0) posmin[i] = pmin;
}

// ============================================================================
// Shared epilogue: per-row max / stable LSE partial / count + atomics.
// ============================================================================
__device__ __forceinline__ void epilogue(f32x4 (&acc)[4][4], int i0, int c0,
        int wr, int wc, int l15, int l4, const float* __restrict__ posmin,
        unsigned* __restrict__ negkey, double* __restrict__ msum,
        unsigned* __restrict__ cntn)
{
    #pragma unroll
    for (int fr = 0; fr < 4; ++fr) {
        #pragma unroll
        for (int reg = 0; reg < 4; ++reg) {
            const int i  = i0 + wr + fr * 16 + l4 * 4 + reg;
            const float th = posmin[i] - EPc;     // strict >
            float vmax = -INFINITY;
            float lM   = -INFINITY;
            float lS   = 0.f;
            int   vcnt = 0;
            float args[4]; bool msk[4];
            #pragma unroll
            for (int fc = 0; fc < 4; ++fc) {
                const int c = c0 + wc + fc * 16 + l15;
                const float s = acc[fr][fc][reg];
                const bool nonown = ((c / 5) != i);
                msk[fc]  = nonown && (s > th);
                args[fc] = BETAc * (s - LMDAc);
                if (nonown)  vmax = fmaxf(vmax, s);
                if (msk[fc]) { vcnt += 1; lM = fmaxf(lM, args[fc]); }
            }
            #pragma unroll
            for (int fc = 0; fc < 4; ++fc)
                if (msk[fc]) lS += __expf(args[fc] - lM);
            #pragma unroll
            for (int m = 1; m < 16; m <<= 1) {
                vmax  = fmaxf(vmax, __shfl_xor(vmax, m, 64));
                vcnt += __shfl_xor(vcnt, m, 64);
                float oM = __shfl_xor(lM, m, 64);
                float oS = __shfl_xor(lS, m, 64);
                if (oS != 0.f) {
                    if (lS == 0.f)      { lM = oM; lS = oS; }
                    else if (lM >= oM)  { lS += oS * __expf(oM - lM); }
                    else                { lS = oS + lS * __expf(lM - oM); lM = oM; }
                }
            }
            if (l15 == 0) {
                atomicMax(&negkey[i], fenc(vmax));
                atomicAdd(&cntn[i], (unsigned)vcnt);
                if (lS > 0.f) {
                    double e = (double)lM - SHIFT;
                    if (e > 690.0) e = 690.0;
                    double Dv = exp(e) * (double)lS;
                    if (!(Dv < 1e300)) Dv = 1e300;    // also catches nan
                    atomicAdd(&msum[i], Dv);
                }
            }
        }
    }
}

// ============================================================================
// Kernel 2 (fast path): MFMA sim GEMM staging pre-split bf16 via global_load_lds.
// 128x128 tile, BK=32, 4 waves, 4x4 frags of 16x16x32 per wave.
// LDS: linear row-major [128][32]bf16 per array; chunk swizzle c^((row>>1)&3)
// applied on the GLOBAL SOURCE address (write side) and the ds_read (read side).
// ============================================================================
__global__ __launch_bounds__(256) void sim_mfma2(const u32* __restrict__ hi,
        const u32* __restrict__ lo, const float* __restrict__ posmin,
        unsigned* __restrict__ negkey, double* __restrict__ msum,
        unsigned* __restrict__ cntn)
{
    __shared__ u32 AsHi[128 * 16];   // 128 rows x 64B
    __shared__ u32 AsLo[128 * 16];
    __shared__ u32 BsHi[128 * 16];
    __shared__ u32 BsLo[128 * 16];

    const int t    = threadIdx.x;
    const int bj   = blockIdx.x % (BB / 128);
    const int bi   = blockIdx.x / (BB / 128);
    const int i0   = bi * 128;
    const int c0   = bj * 128;
    const int lane = t & 63;
    const int w    = t >> 6;
    const int wr   = (w >> 1) * 64;
    const int wc   = (w & 1) * 64;
    const int l15  = lane & 15;
    const int l4   = lane >> 4;

    // ---- staging setup: wave w stages tile rows [w*32, w*32+32) of each array
    const int srow = w * 32 + (lane >> 2);          // j=0 row; j=1 adds 16
    const int scp  = lane & 3;                       // stored chunk slot
    const int sc   = scp ^ ((srow >> 1) & 3);        // logical chunk fetched
    // ((srow+16)>>1)&3 == (srow>>1)&3, so sc is valid for both j=0 and j=1.
    const size_t offA0 = ((size_t)5 * (i0 + srow)      * DD + sc * 8) * 2;
    const size_t offA1 = ((size_t)5 * (i0 + srow + 16) * DD + sc * 8) * 2;
    const size_t offB0 = ((size_t)(c0 + srow)      * DD + sc * 8) * 2;
    const size_t offB1 = ((size_t)(c0 + srow + 16) * DD + sc * 8) * 2;
    const char* gAh0 = (const char*)hi + offA0;
    const char* gAh1 = (const char*)hi + offA1;
    const char* gAl0 = (const char*)lo + offA0;
    const char* gAl1 = (const char*)lo + offA1;
    const char* gBh0 = (const char*)hi + offB0;
    const char* gBh1 = (const char*)hi + offB1;
    const char* gBl0 = (const char*)lo + offB0;
    const char* gBl1 = (const char*)lo + offB1;
    u32* lA0 = AsHi + (w * 32) * 16;        // uniform per wave
    u32* lA1 = AsHi + (w * 32 + 16) * 16;
    u32* lAl0 = AsLo + (w * 32) * 16;
    u32* lAl1 = AsLo + (w * 32 + 16) * 16;
    u32* lB0 = BsHi + (w * 32) * 16;
    u32* lB1 = BsHi + (w * 32 + 16) * 16;
    u32* lBl0 = BsLo + (w * 32) * 16;
    u32* lBl1 = BsLo + (w * 32 + 16) * 16;

    f32x4 acc[4][4];
    #pragma unroll
    for (int a = 0; a < 4; ++a)
        #pragma unroll
        for (int b = 0; b < 4; ++b) acc[a][b] = (f32x4)0.f;

    // precompute swizzled LDS byte offsets for fragment reads
    int aoff[4], boff[4];
    #pragma unroll
    for (int f = 0; f < 4; ++f) {
        const int row = wr + f * 16 + l15;
        const int col = wc + f * 16 + l15;
        aoff[f] = row * 64 + ((l4 ^ ((row >> 1) & 3)) * 16);
        boff[f] = col * 64 + ((l4 ^ ((col >> 1) & 3)) * 16);
    }

    for (int kb = 0; kb < DD; kb += 32) {
        __syncthreads();                       // prev iter's readers done
        GLOAD16(gAh0, lA0);  GLOAD16(gAh1, lA1);
        GLOAD16(gAl0, lAl0); GLOAD16(gAl1, lAl1);
        GLOAD16(gBh0, lB0);  GLOAD16(gBh1, lB1);
        GLOAD16(gBl0, lBl0); GLOAD16(gBl1, lBl1);
        gAh0 += 64; gAh1 += 64; gAl0 += 64; gAl1 += 64;
        gBh0 += 64; gBh1 += 64; gBl0 += 64; gBl1 += 64;
        asm volatile("s_waitcnt vmcnt(0)" ::: "memory");
        __syncthreads();                       // tile visible to all waves

        bf16x8 bh[4], bl[4];
        #pragma unroll
        for (int fc = 0; fc < 4; ++fc) {
            bh[fc] = *(const bf16x8*)((const char*)BsHi + boff[fc]);
            bl[fc] = *(const bf16x8*)((const char*)BsLo + boff[fc]);
        }
        #pragma unroll
        for (int fr = 0; fr < 4; ++fr) {
            bf16x8 ah = *(const bf16x8*)((const char*)AsHi + aoff[fr]);
            bf16x8 al = *(const bf16x8*)((const char*)AsLo + aoff[fr]);
            #pragma unroll
            for (int fc = 0; fc < 4; ++fc) {
                acc[fr][fc] = __builtin_amdgcn_mfma_f32_16x16x32_bf16(ah, bh[fc], acc[fr][fc], 0, 0, 0);
                acc[fr][fc] = __builtin_amdgcn_mfma_f32_16x16x32_bf16(ah, bl[fc], acc[fr][fc], 0, 0, 0);
                acc[fr][fc] = __builtin_amdgcn_mfma_f32_16x16x32_bf16(al, bh[fc], acc[fr][fc], 0, 0, 0);
            }
        }
    }

    epilogue(acc, i0, c0, wr, wc, l15, l4, posmin, negkey, msum, cntn);
}

// ============================================================================
// Kernel 2 (fallback, ws too small): in-kernel cvt, known-good from round 4.
// ============================================================================
__device__ __forceinline__ void cvt8(const float* __restrict__ src,
                                     uint4* __restrict__ dhi, uint4* __restrict__ dlo)
{
    float4 x0 = *(const float4*)(src);
    float4 x1 = *(const float4*)(src + 4);
    float xs[8] = {x0.x, x0.y, x0.z, x0.w, x1.x, x1.y, x1.z, x1.w};
    u32 h[4], l[4];
    #pragma unroll
    for (int p = 0; p < 4; ++p) split2(xs[2*p], xs[2*p+1], &h[p], &l[p]);
    *dhi = make_uint4(h[0], h[1], h[2], h[3]);
    *dlo = make_uint4(l[0], l[1], l[2], l[3]);
}

__global__ __launch_bounds__(256) void sim_mfma(const float* __restrict__ inp,
        const float* __restrict__ posmin, unsigned* __restrict__ negkey,
        double* __restrict__ msum, unsigned* __restrict__ cntn)
{
    __shared__ uint4 AsHi[128][4];
    __shared__ uint4 AsLo[128][4];
    __shared__ uint4 BsHi[128][4];
    __shared__ uint4 BsLo[128][4];

    const int t    = threadIdx.x;
    const int bj   = blockIdx.x % (BB / 128);
    const int bi   = blockIdx.x / (BB / 128);
    const int i0   = bi * 128;
    const int c0   = bj * 128;
    const int lane = t & 63;
    const int w    = t >> 6;
    const int wr   = (w >> 1) * 64;
    const int wc   = (w & 1) * 64;
    const int l15  = lane & 15;
    const int l4   = lane >> 4;

    f32x4 acc[4][4];
    #pragma unroll
    for (int a = 0; a < 4; ++a)
        #pragma unroll
        for (int b = 0; b < 4; ++b) acc[a][b] = (f32x4)0.f;

    const int r0  = t >> 2;
    const int ch0 = t & 3;

    for (int kb = 0; kb < DD; kb += 32) {
        __syncthreads();
        #pragma unroll
        for (int half = 0; half < 2; ++half) {
            const int row = r0 + half * 64;
            const int cs  = ch0 ^ ((row >> 2) & 3);
            cvt8(inp + (size_t)(5 * (i0 + row)) * DD + kb + ch0 * 8,
                 &AsHi[row][cs], &AsLo[row][cs]);
            cvt8(inp + (size_t)(c0 + row) * DD + kb + ch0 * 8,
                 &BsHi[row][cs], &BsLo[row][cs]);
        }
        __syncthreads();

        bf16x8 bh[4], bl[4];
        #pragma unroll
        for (int fc = 0; fc < 4; ++fc) {
            const int col = wc + fc * 16 + l15;
            const int cs  = l4 ^ ((col >> 2) & 3);
            bh[fc] = *(const bf16x8*)&BsHi[col][cs];
            bl[fc] = *(const bf16x8*)&BsLo[col][cs];
        }
        #pragma unroll
        for (int fr = 0; fr < 4; ++fr) {
            const int row = wr + fr * 16 + l15;
            const int cs  = l4 ^ ((row >> 2) & 3);
            bf16x8 ah = *(const bf16x8*)&AsHi[row][cs];
            bf16x8 al = *(const bf16x8*)&AsLo[row][cs];
            #pragma unroll
            for (int fc = 0; fc < 4; ++fc) {
                acc[fr][fc] = __builtin_amdgcn_mfma_f32_16x16x32_bf16(ah, bh[fc], acc[fr][fc], 0, 0, 0);
                acc[fr][fc] = __builtin_amdgcn_mfma_f32_16x16x32_bf16(ah, bl[fc], acc[fr][fc], 0, 0, 0);
                acc[fr][fc] = __builtin_amdgcn_mfma_f32_16x16x32_bf16(al, bh[fc], acc[fr][fc], 0, 0, 0);
            }
        }
    }

    epilogue(acc, i0, c0, wr, wc, l15, l4, posmin, negkey, msum, cntn);
}

// ============================================================================
// Kernel 3: finalize.
// ============================================================================
__global__ __launch_bounds__(1024) void fin_kernel(const float* __restrict__ pos,
        const unsigned* __restrict__ negkey, const double* __restrict__ msum,
        const unsigned* __restrict__ cntn, float* __restrict__ out)
{
    const int t = threadIdx.x;
    double lossAcc = 0.0;
    int pAcc = 0, nAcc = 0;
    for (int r = t; r < NB; r += 1024) {
        const float negmax = fdec(negkey[r]);
        const float thr = negmax + EPc;       // strict <
        float Mp = -INFINITY; int pc = 0;
        float pa[4]; bool pm[4];
        #pragma unroll
        for (int g = 0; g < 4; ++g) {
            const float p = pos[r * 4 + g];
            pa[g] = -ALPHAc * (p - LMDAc);
            pm[g] = (p < thr);
            if (pm[g]) { pc += 1; Mp = fmaxf(Mp, pa[g]); }
        }
        double lp = 0.0;
        if (pc > 0) {
            float sp = 0.f;
            #pragma unroll
            for (int g = 0; g < 4; ++g)
                if (pm[g]) sp += __expf(pa[g] - Mp);
            double a = (double)Mp + log((double)sp);
            lp = (a > 30.0 ? a : log1p(exp(a))) / (double)ALPHAc;
        }
        double ln = 0.0;
        double Dsum = msum[r];
        if (Dsum > 0.0) {
            double a = SHIFT + log(Dsum);
            ln = (a > 30.0 ? a : log1p(exp(a))) / (double)BETAc;
        }
        double contrib = lp + ln;
        if (!(contrib < 1e30)) contrib = 1e30;
        lossAcc += contrib;
        pAcc += pc;
        nAcc += (int)cntn[r];
    }
    __shared__ double sl[1024];
    __shared__ int    sp_[1024];
    __shared__ int    sn_[1024];
    sl[t] = lossAcc; sp_[t] = pAcc; sn_[t] = nAcc;
    __syncthreads();
    for (int s = 512; s > 0; s >>= 1) {
        if (t < s) { sl[t] += sl[t + s]; sp_[t] += sp_[t + s]; sn_[t] += sn_[t + s]; }
        __syncthreads();
    }
    if (t == 0) {
        double loss = sl[0] / 4096.0;
        if (!(loss < 1e30)) loss = 1e30;
        out[0] = (float)loss;
        out[1] = (float)sp_[0] / 16384.0f;
        out[2] = (float)sn_[0] / 83865600.0f;
    }
}

// ============================================================================
extern "C" void kernel_launch(void* const* d_in, const int* in_sizes, int n_in,
                              void* d_out, int out_size, void* d_ws, size_t ws_size,
                              hipStream_t stream)
{
    (void)in_sizes; (void)n_in; (void)out_size;
    const float* inp = (const float*)d_in[0];   // (20480, 512) f32; targets unused
    char* ws = (char*)d_ws;
    // ws layout (bytes):
    //   [0      , 65536 )  pos      : 4096*4 f32
    //   [65536  , 81920 )  posmin   : 4096 f32
    //   [81920  , 98304 )  negkey   : 4096 u32
    //   [98304  , 131072)  msum     : 4096 f64
    //   [131072 , 147456)  cntn     : 4096 u32
    //   [147456 , +21.0MB)  Hi bf16 [BB][DD]
    //   [ ...   , +21.0MB)  Lo bf16 [BB][DD]
    float*    pos    = (float*)   (ws);
    float*    posmin = (float*)   (ws + 65536);
    unsigned* negkey = (unsigned*)(ws + 81920);
    double*   msum   = (double*)  (ws + 98304);
    unsigned* cntn   = (unsigned*)(ws + 131072);
    u32*      hi     = (u32*)     (ws + 147456);
    u32*      lo     = (u32*)     (ws + 147456 + (size_t)BB * DD * 2);
    float*    out    = (float*)d_out;
    const size_t need = 147456 + (size_t)BB * DD * 4;   // 42.1 MB

    hipMemsetAsync(ws + 81920, 0, 65536, stream);
    hipLaunchKernelGGL(pos_kernel, dim3(NB / 4), dim3(256), 0, stream, inp, pos, posmin);

    if (ws_size >= need) {
        hipLaunchKernelGGL(split_kernel, dim3(BB * DD / (256 * 8)), dim3(256), 0, stream,
                           inp, hi, lo);
        hipLaunchKernelGGL(sim_mfma2, dim3((NB / 128) * (BB / 128)), dim3(256), 0, stream,
                           hi, lo, posmin, negkey, msum, cntn);
    } else {
        hipLaunchKernelGGL(sim_mfma, dim3((NB / 128) * (BB / 128)), dim3(256), 0, stream,
                           inp, posmin, negkey, msum, cntn);
    }
    hipLaunchKernelGGL(fin_kernel, dim3(1), dim3(1024), 0, stream, pos, negkey, msum, cntn, out);
}